// Round 2
// 222.726 us; speedup vs baseline: 1.1692x; 1.1692x over previous
//
#include <hip/hip_runtime.h>
#include <math.h>

// QuadraticNetCholesky via MFMA: out[b] = L L^T, tril(L) = softplus(MLP(x[b])),
// MLP 12 -> 128 (ELU) -> 32 (ELU) -> 78 (softplus).
//
// Round-4 structure (MFMA, f16 split planes):
//  - Every layer computed as H = W · X^T with v_mfma_f32_16x16x32_f16:
//    weights are the A operand (rows = out-features), samples are the N dim.
//    With this orientation the D fragment of layer n (col=lane&15=sample,
//    row=4*(lane>>4)+reg=feature) IS the B fragment of layer n+1
//    (col=lane&15, k = {4h+j} U {16+4h+j}) -> no inter-layer transposes.
//  - Precision: split-f16 (hi = RN_f16(v), lo = RN_f16(v-hi)); each GEMM is
//    3 MFMAs: Ah*Bh + Ah*Bl + Al*Bh, fp32 accumulate. Per-product rel error
//    ~3*2^-24 (f16 11-bit mantissa) — effectively fp32. Round 3's bf16 planes
//    (~2^-14) failed absmax 0.547 > 0.1625; f16 is the same cost, 1000x tighter.
//  - Weights pre-split + pre-swizzled into fragment layout in LDS once per
//    block (35 KB). Bias rides as the MFMA C initializer.
//  - L L^T on VALU, 4 lanes/sample (3 rows each) with static-index template
//    dispatch; output goes through the proven 64-sample LDS staging buffer
//    so global writes stay perfectly coalesced (149.5 MB ~= ideal).
//  - LDS: weights 35 KB + stage 37.9 KB = 72 KB -> 2 blocks/CU; x-staging and
//    per-wave L-scratch overlay the stage buffer. Grid = 1024 blocks.

namespace {

constexpr int ND  = 12;
constexpr int BLK = 256;   // threads/block (4 waves)
constexpr int SPB = 256;   // samples/block (wave w, group g: samples g*64+w*16+s)

typedef __attribute__((ext_vector_type(8))) _Float16 h8t;  // 8 f16 = 4 VGPR
typedef __attribute__((ext_vector_type(4))) float    f4t;  // mfma acc

union FragU { h8t v; _Float16 s[8]; unsigned u[4]; };

// ---- LDS byte offsets ----
constexpr int oW1h = 0;        // 8 tiles * 64 lanes * 4 f16 (K-half 1 is all zero)
constexpr int oW1l = 4096;
constexpr int oW2h = 8192;     // 8 tiles (kt*2+mt) * 64 * 8 f16
constexpr int oW2l = 16384;
constexpr int oW3h = 24576;    // 5 tiles * 64 * 8 f16
constexpr int oW3l = 29696;
constexpr int oB1B = 34816;    // 128 f32
constexpr int oB2B = 35328;    // 32 f32
constexpr int oB3B = 35456;    // 80 f32 (78 + zero pad)
constexpr int oStgB = 35776;   // stage: 64 samples * 148 f32 = 37888 B
constexpr int LDSB  = 73664;   // total bytes -> 2 blocks/CU

constexpr int oB1F = oB1B / 4, oB2F = oB2B / 4, oB3F = oB3B / 4;
constexpr int oStgF = oStgB / 4;
constexpr int STRIDE = 148;    // f32 stride per staged sample (144 + pad)

__device__ __forceinline__ float elu_f(float v) {
    return v > 0.0f ? v : __expf(v) - 1.0f;
}
__device__ __forceinline__ float softplus_f(float v) {
    return fmaxf(v, 0.0f) + __logf(1.0f + __expf(-fabsf(v)));
}

// G rows I0..I0+2 of L L^T for this lane's sample; all indices static after
// unroll (rule #20: no runtime VGPR-array indexing).
template<int I0>
__device__ __forceinline__ void gRows(const float (&L)[80], float* dst) {
    #pragma unroll
    for (int i = I0; i < I0 + 3; ++i) {
        float r[12];
        #pragma unroll
        for (int k = 0; k < 12; ++k) {
            const int mm = (i < k) ? i : k;
            float s0 = 0.f, s1 = 0.f;
            #pragma unroll
            for (int j = 0; j <= mm; ++j) {
                const float pr = L[i*(i+1)/2 + j] * L[k*(k+1)/2 + j];
                if (j & 1) s1 += pr; else s0 += pr;
            }
            r[k] = s0 + s1;
        }
        *(f4t*)(dst + i*12 + 0) = (f4t){r[0], r[1], r[2],  r[3]};
        *(f4t*)(dst + i*12 + 4) = (f4t){r[4], r[5], r[6],  r[7]};
        *(f4t*)(dst + i*12 + 8) = (f4t){r[8], r[9], r[10], r[11]};
    }
}

__global__ __launch_bounds__(BLK, 2) void qnc(
    const float* __restrict__ x,
    const float* __restrict__ W1, const float* __restrict__ b1,
    const float* __restrict__ W2, const float* __restrict__ b2,
    const float* __restrict__ W3, const float* __restrict__ b3,
    float* __restrict__ out)
{
    __shared__ __align__(16) unsigned char ldsB[LDSB];
    float*     ldsF = (float*)ldsB;
    _Float16*  sW1h = (_Float16*)(ldsB + oW1h);
    _Float16*  sW1l = (_Float16*)(ldsB + oW1l);
    _Float16*  sW2h = (_Float16*)(ldsB + oW2h);
    _Float16*  sW2l = (_Float16*)(ldsB + oW2l);
    _Float16*  sW3h = (_Float16*)(ldsB + oW3h);
    _Float16*  sW3l = (_Float16*)(ldsB + oW3l);

    const int t = threadIdx.x;
    const int lane = t & 63, w = t >> 6;
    const int sIn = lane & 15, h = lane >> 4;      // sample-in-tile, k/row quarter
    const int sbase = blockIdx.x * SPB;

    // ================= one-time weight staging (split + frag swizzle) ========
    // W1 as A frags: tile m rows 16m..16m+15 of 128, k = 4h+j (K-half1 == 0).
    for (int i = t; i < 2048; i += BLK) {
        const int m = i >> 8, l = (i >> 2) & 63, j = i & 3;
        const int row = 16*m + (l & 15), k = 4*(l >> 4) + j;
        const float v = (k < ND) ? W1[row*ND + k] : 0.0f;
        const _Float16 hi = (_Float16)v;
        sW1h[i] = hi;
        sW1l[i] = (_Float16)(v - (float)hi);
    }
    // W2 as A frags: tile t2 = kt*2+mt; rows 16mt.., k = 32kt + {4h+j | 16+4h+j}.
    for (int i = t; i < 4096; i += BLK) {
        const int t2 = i >> 9, l = (i >> 3) & 63, j = i & 7;
        const int kt = t2 >> 1, mt = t2 & 1, hq = l >> 4;
        const int row = 16*mt + (l & 15);
        const int k = 32*kt + ((j < 4) ? 4*hq + j : 16 + 4*hq + (j - 4));
        const float v = W2[row*128 + k];
        const _Float16 hi = (_Float16)v;
        sW2h[i] = hi;
        sW2l[i] = (_Float16)(v - (float)hi);
    }
    // W3 as A frags: tile mt rows 16mt.. (rows >= 78 zero-padded), k = 0..31.
    for (int i = t; i < 2560; i += BLK) {
        const int mt = i >> 9, l = (i >> 3) & 63, j = i & 7;
        const int hq = l >> 4;
        const int row = 16*mt + (l & 15);
        const int k = (j < 4) ? 4*hq + j : 16 + 4*hq + (j - 4);
        const float v = (row < 78) ? W3[row*32 + k] : 0.0f;
        const _Float16 hi = (_Float16)v;
        sW3h[i] = hi;
        sW3l[i] = (_Float16)(v - (float)hi);
    }
    for (int i = t; i < 128; i += BLK) ldsF[oB1F + i] = b1[i];
    for (int i = t; i < 32;  i += BLK) ldsF[oB2F + i] = b2[i];
    for (int i = t; i < 80;  i += BLK) ldsF[oB3F + i] = (i < 78) ? b3[i] : 0.0f;

    // x staged (overlaying the stage buffer): 256 samples * 12 f32, coalesced.
    {
        const float4* xg = (const float4*)(x + (long)sbase * ND);
        float4* xs = (float4*)(ldsB + oStgB);
        for (int i = t; i < 768; i += BLK) xs[i] = xg[i];
    }
    __syncthreads();

    // ---- prebuild B1 (x^T) frags for all 4 groups, packed hi/lo words ----
    // B[k][sample]: k = 4h+j for elems 0-3 (k<12 real, h==3 -> 0), elems 4-7 = 0.
    unsigned B1h[4][2], B1l[4][2];
    #pragma unroll
    for (int g = 0; g < 4; ++g) {
        float xv[4] = {0.f, 0.f, 0.f, 0.f};
        if (h < 3) {
            const float4 q = *(const float4*)(ldsF + oStgF + (g*64 + w*16 + sIn)*ND + 4*h);
            xv[0] = q.x; xv[1] = q.y; xv[2] = q.z; xv[3] = q.w;
        }
        FragU bh, bl;
        #pragma unroll
        for (int j = 0; j < 4; ++j) {
            const _Float16 hi = (_Float16)xv[j];
            bh.s[j] = hi;
            bl.s[j] = (_Float16)(xv[j] - (float)hi);
        }
        B1h[g][0] = bh.u[0]; B1h[g][1] = bh.u[1];
        B1l[g][0] = bl.u[0]; B1l[g][1] = bl.u[1];
    }
    __syncthreads();   // x region is dead; stage buffer free for L/G use

    // ================= per-group pipeline ===================================
    for (int g = 0; g < 4; ++g) {
        // static select of this group's B1 frag words (keeps arrays static)
        unsigned xh0 = 0, xh1 = 0, xl0 = 0, xl1 = 0;
        #pragma unroll
        for (int gg = 0; gg < 4; ++gg)
            if (gg == g) { xh0 = B1h[gg][0]; xh1 = B1h[gg][1];
                           xl0 = B1l[gg][0]; xl1 = B1l[gg][1]; }
        FragU bh; bh.u[0] = xh0; bh.u[1] = xh1; bh.u[2] = 0; bh.u[3] = 0;
        FragU bl; bl.u[0] = xl0; bl.u[1] = xl1; bl.u[2] = 0; bl.u[3] = 0;

        // ---- layer 1: D1[m] = W1 * x^T + b1   (8 tiles of 16 features) ----
        f4t d1[8];
        #pragma unroll
        for (int m = 0; m < 8; ++m) {
            f4t c = *(const f4t*)(ldsF + oB1F + 16*m + 4*h);   // bias init
            FragU Ah, Al;
            { const uint2 p = *(const uint2*)(ldsB + oW1h + (m*64 + lane)*8);
              Ah.u[0] = p.x; Ah.u[1] = p.y; Ah.u[2] = 0; Ah.u[3] = 0; }
            { const uint2 p = *(const uint2*)(ldsB + oW1l + (m*64 + lane)*8);
              Al.u[0] = p.x; Al.u[1] = p.y; Al.u[2] = 0; Al.u[3] = 0; }
            c = __builtin_amdgcn_mfma_f32_16x16x32_f16(Ah.v, bh.v, c, 0, 0, 0);
            c = __builtin_amdgcn_mfma_f32_16x16x32_f16(Ah.v, bl.v, c, 0, 0, 0);
            d1[m] = __builtin_amdgcn_mfma_f32_16x16x32_f16(Al.v, bh.v, c, 0, 0, 0);
        }

        // ---- ELU + split-pack into B2 frags (K-step kt = D-tiles 2kt,2kt+1) ----
        FragU b2h[4], b2l[4];
        #pragma unroll
        for (int kt = 0; kt < 4; ++kt) {
            #pragma unroll
            for (int r = 0; r < 4; ++r) {
                const float e0 = elu_f(d1[2*kt][r]);
                const float e1 = elu_f(d1[2*kt + 1][r]);
                const _Float16 h0 = (_Float16)e0;
                const _Float16 h1 = (_Float16)e1;
                b2h[kt].s[r]     = h0;
                b2l[kt].s[r]     = (_Float16)(e0 - (float)h0);
                b2h[kt].s[4 + r] = h1;
                b2l[kt].s[4 + r] = (_Float16)(e1 - (float)h1);
            }
        }

        // ---- layer 2: 2 feature-tiles x 4 K-steps; main + cross acc chains ----
        f4t a2m[2], a2c[2];
        #pragma unroll
        for (int mt = 0; mt < 2; ++mt) {
            a2m[mt] = *(const f4t*)(ldsF + oB2F + 16*mt + 4*h);
            a2c[mt] = (f4t){0.f, 0.f, 0.f, 0.f};
        }
        #pragma unroll
        for (int kt = 0; kt < 4; ++kt) {
            #pragma unroll
            for (int mt = 0; mt < 2; ++mt) {
                const int t2 = kt*2 + mt;
                FragU Ah, Al;
                Ah.v = *(const h8t*)(ldsB + oW2h + (t2*64 + lane)*16);
                Al.v = *(const h8t*)(ldsB + oW2l + (t2*64 + lane)*16);
                a2m[mt] = __builtin_amdgcn_mfma_f32_16x16x32_f16(Ah.v, b2h[kt].v, a2m[mt], 0, 0, 0);
                a2c[mt] = __builtin_amdgcn_mfma_f32_16x16x32_f16(Ah.v, b2l[kt].v, a2c[mt], 0, 0, 0);
                a2c[mt] = __builtin_amdgcn_mfma_f32_16x16x32_f16(Al.v, b2h[kt].v, a2c[mt], 0, 0, 0);
            }
        }

        // ---- ELU + split-pack into the single layer-3 B frag (K=32) ----
        FragU b3hF, b3lF;
        #pragma unroll
        for (int r = 0; r < 4; ++r) {
            const float e0 = elu_f(a2m[0][r] + a2c[0][r]);
            const float e1 = elu_f(a2m[1][r] + a2c[1][r]);
            const _Float16 h0 = (_Float16)e0;
            const _Float16 h1 = (_Float16)e1;
            b3hF.s[r]     = h0;
            b3lF.s[r]     = (_Float16)(e0 - (float)h0);
            b3hF.s[4 + r] = h1;
            b3lF.s[4 + r] = (_Float16)(e1 - (float)h1);
        }

        // ---- layer 3 + softplus: v[t] for t = 16mt + 4h + r, sample = sIn ----
        float* Lw = ldsF + oStgF + w*2368;     // wave-private L scratch (16 x 84)
        #pragma unroll
        for (int mt = 0; mt < 5; ++mt) {
            f4t c = *(const f4t*)(ldsF + oB3F + 16*mt + 4*h);
            FragU Ah, Al;
            Ah.v = *(const h8t*)(ldsB + oW3h + (mt*64 + lane)*16);
            Al.v = *(const h8t*)(ldsB + oW3l + (mt*64 + lane)*16);
            c = __builtin_amdgcn_mfma_f32_16x16x32_f16(Ah.v, b3hF.v, c, 0, 0, 0);
            c = __builtin_amdgcn_mfma_f32_16x16x32_f16(Ah.v, b3lF.v, c, 0, 0, 0);
            c = __builtin_amdgcn_mfma_f32_16x16x32_f16(Al.v, b3hF.v, c, 0, 0, 0);
            f4t s;
            s[0] = softplus_f(c[0]); s[1] = softplus_f(c[1]);
            s[2] = softplus_f(c[2]); s[3] = softplus_f(c[3]);
            *(f4t*)(Lw + sIn*84 + 16*mt + 4*h) = s;    // wave-local, no barrier
        }

        // ---- gather full L[78] for this lane's sample (4 lanes/sample) ----
        float L[80];
        #pragma unroll
        for (int jq = 0; jq < 20; ++jq) {
            const f4t q = *(const f4t*)(Lw + sIn*84 + 4*jq);
            L[4*jq + 0] = q[0]; L[4*jq + 1] = q[1];
            L[4*jq + 2] = q[2]; L[4*jq + 3] = q[3];
        }

        // ---- G = L L^T, 3 rows per lane-quarter, staged at 148-f32 stride ----
        float* stg = ldsF + oStgF + (w*16 + sIn) * STRIDE;
        if      (h == 0) gRows<0>(L, stg);
        else if (h == 1) gRows<3>(L, stg);
        else if (h == 2) gRows<6>(L, stg);
        else             gRows<9>(L, stg);

        __syncthreads();
        // ---- coalesced copy-out of this group's 64 contiguous samples ----
        float4* g4 = (float4*)(out + (long)(sbase + g*64) * 144);
        for (int u = t; u < 2304; u += BLK) {      // 9 iters exactly
            const int s = u / 36, q = u - s * 36;
            g4[u] = *(const float4*)(ldsF + oStgF + s * STRIDE + q * 4);
        }
        __syncthreads();
    }
}

} // namespace

extern "C" void kernel_launch(void* const* d_in, const int* in_sizes, int n_in,
                              void* d_out, int out_size, void* d_ws, size_t ws_size,
                              hipStream_t stream) {
    const float* x  = (const float*)d_in[0];
    const float* W1 = (const float*)d_in[1];
    const float* b1 = (const float*)d_in[2];
    const float* W2 = (const float*)d_in[3];
    const float* b2 = (const float*)d_in[4];
    const float* W3 = (const float*)d_in[5];
    const float* b3 = (const float*)d_in[6];
    float* out = (float*)d_out;

    const int batch  = in_sizes[0] / ND;      // 262144, divisible by SPB=256
    const int blocks = batch / SPB;           // 1024 blocks (2 resident/CU)

    qnc<<<blocks, BLK, 0, stream>>>(x, W1, b1, W2, b2, W3, b3, out);
}